// Round 16
// baseline (419.619 us; speedup 1.0000x reference)
//
#include <hip/hip_runtime.h>

typedef unsigned char u8;
typedef unsigned short u16;
typedef unsigned int u32;
typedef unsigned long long u64;
typedef __attribute__((ext_vector_type(8))) short short8;
typedef __attribute__((ext_vector_type(4))) float f32x4;

#define NB 64
#define LL 4096
#define CC 512
#define KK 2048     // kept tokens (extra token at row KK)
#define PPQ 819     // P
#define HH 102      // H
#define KP 2176     // padded all_tokens rows (34*64)
#define PPAD 896    // padded P
#define HP 128      // padded H
#define NCH 34      // 64-k chunks in KP (layout)
#define NRUN 33     // chunks processed (covers k <= 2111; rest all-zero)
#define NPT 13      // p-tiles of 64

__device__ __forceinline__ u16 f2bf(float f) {
  u32 u = __float_as_uint(f);
  u += 0x7fffu + ((u >> 16) & 1u);
  return (u16)(u >> 16);
}
__device__ __forceinline__ float bf2f(u16 h) { return __uint_as_float(((u32)h) << 16); }
__device__ __forceinline__ float dec_score(u32 s) {
  u32 u = (s & 0x80000000u) ? (s ^ 0x80000000u) : ~s;
  return __uint_as_float(u);
}
__device__ __forceinline__ u8 f2fp8(float f) {
  return (u8)(__builtin_amdgcn_cvt_pk_fp8_f32(f, 0.f, 0, false) & 0xff);
}

// ---------- sort (blocks 0..63) + weight prep (blocks 64..239) ----------
__global__ __launch_bounds__(1024) void sort_prep_kernel(
    const float* __restrict__ ax, const float* __restrict__ ay,
    u64* __restrict__ keys, float* __restrict__ mask_out, float2* __restrict__ stats,
    const float* __restrict__ w1, const float* __restrict__ w2,
    u16* __restrict__ w1T, u8* __restrict__ w2T8)
{
  if (blockIdx.x >= NB) {
    int id = (blockIdx.x - NB)*1024 + threadIdx.x;
    if (id < HP*CC) {
      int r = id >> 9, c = id & 511;
      w1T[id] = (r < HH) ? f2bf(w1[c*HH + r]) : (u16)0;
    } else {
      int id2 = id - HP*CC;
      if (id2 < PPAD*HP) {
        int r = id2 >> 7, c = id2 & 127;
        w2T8[id2] = (r < PPQ && c < HH) ? f2fp8(16.0f*w2[(size_t)c*PPQ + r]) : (u8)0;
      }
    }
    return;
  }
  __shared__ u64 arr[LL];
  __shared__ float red[16];
  int b = blockIdx.x, tid = threadIdx.x;
  for (int i = tid; i < LL; i += 1024) {
    float s = ax[(size_t)b*LL + i] + ay[(size_t)b*LL + i];
    u32 u = __float_as_uint(s);
    u = (u & 0x80000000u) ? ~u : (u | 0x80000000u);
    arr[i] = (((u64)u) << 32) | (u32)(LL - 1 - i);
  }
  __syncthreads();
  for (int k = 2; k <= LL; k <<= 1) {
    for (int j = k >> 1; j > 0; j >>= 1) {
      #pragma unroll
      for (int rep = 0; rep < 4; ++rep) {
        int i = tid + rep * 1024;
        int ixj = i ^ j;
        if (ixj > i) {
          u64 a = arr[i], c = arr[ixj];
          bool desc = ((i & k) == 0);
          if (desc ? (a < c) : (a > c)) { arr[i] = c; arr[ixj] = a; }
        }
      }
      __syncthreads();
    }
  }
  for (int i = tid; i < LL; i += 1024) {
    u64 v = arr[i];
    keys[(size_t)b*LL + i] = v;
    int idx = (LL - 1) - (int)(v & 0xffffffffu);
    mask_out[(size_t)b*LL + idx] = (i < KK) ? 1.0f : 0.0f;
  }
  float m = dec_score((u32)(arr[KK] >> 32));
  float part = 0.f;
  for (int i = KK + tid; i < LL; i += 1024)
    part += expf(dec_score((u32)(arr[i] >> 32)) - m);
  #pragma unroll
  for (int off = 32; off; off >>= 1) part += __shfl_xor(part, off);
  if ((tid & 63) == 0) red[tid >> 6] = part;
  __syncthreads();
  if (tid == 0) {
    float s = 0.f;
    #pragma unroll
    for (int i = 0; i < 16; ++i) s += red[i];
    stats[b] = make_float2(m, s);
  }
}

// ---------- tail weighted partial sums (extra token) ----------
__global__ __launch_bounds__(256) void tail_partial_kernel(
    const float* __restrict__ tokens, const u64* __restrict__ keys,
    const float2* __restrict__ stats, float* __restrict__ partials)
{
  int b = blockIdx.y, rb = blockIdx.x, t = threadIdx.x;
  float m = stats[b].x, inv = 1.0f / stats[b].y;
  const u64* kb = keys + (size_t)b*LL + KK + rb*256;
  float a0 = 0.f, a1 = 0.f;
  #pragma unroll 4
  for (int r = 0; r < 256; ++r) {
    u64 kk = kb[r];
    int idx = (LL - 1) - (int)(kk & 0xffffffffu);
    float w = expf(dec_score((u32)(kk >> 32)) - m) * inv;
    const float* src = tokens + ((size_t)b*LL + idx)*CC;
    a0 += w * src[t];
    a1 += w * src[t + 256];
  }
  float* dst = partials + (size_t)(b*8 + rb)*CC;
  dst[t] = a0; dst[t + 256] = a1;
}

// ---------- gather + LN + transpose-to-fp8 + MLP GEMM ----------
__global__ __launch_bounds__(512) void gather_ln_mlp_kernel(
    const float* __restrict__ tokens, const u64* __restrict__ keys,
    const float* __restrict__ partials,
    const u16* __restrict__ w1T,    // [128][512] bf16
    const float* __restrict__ b1,
    const float* __restrict__ ln_g, const float* __restrict__ ln_b,
    u8* __restrict__ allTT, u8* __restrict__ hbuf8)
{
  __shared__ u16 t[64*512];
  __shared__ float2 rst[64];
  int b = blockIdx.y;
  int r0 = blockIdx.x*64;
  int tid = threadIdx.x, lane = tid & 63, wave = tid >> 6;

  // ---- phase 1 ----
  #pragma unroll
  for (int i = 0; i < 8; ++i) {
    int rr = wave*8 + i;
    int r = r0 + rr;
    float x[8];
    if (r < KK) {
      u64 kk = keys[(size_t)b*LL + r];
      int idx = (LL - 1) - (int)(kk & 0xffffffffu);
      const float* src = tokens + ((size_t)b*LL + idx)*CC + lane*8;
      f32x4 v0 = *(const f32x4*)src;
      f32x4 v1 = *(const f32x4*)(src + 4);
      #pragma unroll
      for (int j = 0; j < 4; ++j) { x[j] = v0[j]; x[j+4] = v1[j]; }
    } else if (r == KK) {
      #pragma unroll
      for (int j = 0; j < 8; ++j) {
        float s = 0.f;
        #pragma unroll
        for (int p = 0; p < 8; ++p) s += partials[(size_t)(b*8 + p)*CC + lane*8 + j];
        x[j] = s;
      }
    } else {
      #pragma unroll
      for (int j = 0; j < 8; ++j) x[j] = 0.f;
    }
    float s = 0.f;
    #pragma unroll
    for (int j = 0; j < 8; ++j) s += x[j];
    #pragma unroll
    for (int off = 32; off; off >>= 1) s += __shfl_xor(s, off);
    float mu = s * (1.0f/CC);
    float vs = 0.f;
    #pragma unroll
    for (int j = 0; j < 8; ++j) { float d = x[j] - mu; vs += d*d; }
    #pragma unroll
    for (int off = 32; off; off >>= 1) vs += __shfl_xor(vs, off);
    float rstd = rsqrtf(vs * (1.0f/CC) + 1e-5f);
    short8 raw;
    #pragma unroll
    for (int j = 0; j < 8; ++j) raw[j] = (short)f2bf(x[j]);
    *(short8*)(t + rr*512 + ((lane ^ (rr & 7)) << 3)) = raw;
    if (lane == 0) rst[rr] = make_float2(mu, rstd);
  }
  __syncthreads();

  // ---- phase 2: column c = tid; allTT fragment layout [cgrp][sl2][lane][8] ----
  {
    int c = tid;
    u8* dstg = allTT + ((size_t)(b*NCH + blockIdx.x))*(CC*64) + (size_t)(c >> 4)*1024;
    int ln16 = c & 15;
    int cu = c >> 3, cl = c & 7;
    float g = ln_g[c], bb = ln_b[c];
    #pragma unroll
    for (int g8 = 0; g8 < 8; ++g8) {
      float f[8];
      int ri[8];
      #pragma unroll
      for (int j = 0; j < 8; ++j) {
        int rr = g8*8 + j;
        ri[j] = rr*512 + (((cu ^ (rr & 7)) << 3) | cl);
        f[j] = bf2f(t[ri[j]]);
      }
      u32 lo = __builtin_amdgcn_cvt_pk_fp8_f32(f[0], f[1], 0, false);
      lo = __builtin_amdgcn_cvt_pk_fp8_f32(f[2], f[3], lo, true);
      u32 hi = __builtin_amdgcn_cvt_pk_fp8_f32(f[4], f[5], 0, false);
      hi = __builtin_amdgcn_cvt_pk_fp8_f32(f[6], f[7], hi, true);
      *(uint2*)(dstg + (g8 >> 2)*512 + (ln16 + (g8 & 3)*16)*8) = make_uint2(lo, hi);
      #pragma unroll
      for (int j = 0; j < 8; ++j) {
        int rr = g8*8 + j;
        float2 st = rst[rr];
        t[ri[j]] = f2bf((f[j] - st.x)*st.y*g + bb);
      }
    }
  }
  __syncthreads();

  // ---- phase 3: 64x128x512 GEMM -> fp8(4*gelu), LDS-restaged coalesced store ----
  {
    int colh = wave*16 + (lane & 15);
    f32x4 hacc[4];
    #pragma unroll
    for (int m = 0; m < 4; ++m) hacc[m] = (f32x4){0.f,0.f,0.f,0.f};
    for (int kt = 0; kt < 16; ++kt) {
      short8 bf = *(const short8*)(w1T + (size_t)colh*CC + kt*32 + (lane >> 4)*8);
      int ku = kt*4 + (lane >> 4);
      #pragma unroll
      for (int m = 0; m < 4; ++m) {
        int row = m*16 + (lane & 15);
        short8 afr = *(const short8*)(t + row*512 + ((ku ^ (row & 7)) << 3));
        hacc[m] = __builtin_amdgcn_mfma_f32_16x16x32_bf16(afr, bf, hacc[m], 0, 0, 0);
      }
    }
    __syncthreads();   // all waves done reading t -> reuse as staging
    u8* stage = (u8*)t;
    float bb = (colh < HH) ? b1[colh] : 0.f;
    int s4 = colh >> 5;
    int lq = (colh >> 3) & 3;
    int hbyte = colh & 7;
    #pragma unroll
    for (int m = 0; m < 4; ++m)
      #pragma unroll
      for (int q = 0; q < 4; ++q) {
        int rk = m*16 + (lane >> 4)*4 + q;
        float rv = 0.f;
        if (colh < HH) {
          float xx = hacc[m][q] + bb;
          rv = 0.5f*xx*(1.0f + erff(xx*0.70710678118654752f));
        }
        stage[((rk >> 4)*4 + s4)*512 + ((rk & 15) + lq*16)*8 + hbyte] = f2fp8(4.0f*rv);
      }
    __syncthreads();
    u8* hb = hbuf8 + (size_t)(b*NCH + blockIdx.x)*8192;
    *(uint4*)(hb + tid*16) = *(const uint4*)(stage + tid*16);
  }
}

// ---------- fused v12: reg-resident w2 frags, no w2s LDS ----------
template<bool MASKED>
__device__ __forceinline__ void v9_logits(
    const long (&af)[4], const long (&w2f)[2][4], const float (&b2s2)[2],
    float sc2, int kcAbs, int kf, int pfb, int lane,
    float (&s_acc)[2], u8* psbuf)
{
  #pragma unroll
  for (int j = 0; j < 2; ++j) {
    int pr = (pfb + j)*16 + (lane & 15);
    f32x4 Lacc = (f32x4){0.f,0.f,0.f,0.f};
    #pragma unroll
    for (int s4 = 0; s4 < 4; ++s4)
      Lacc = __builtin_amdgcn_mfma_f32_16x16x32_fp8_fp8(af[s4], w2f[j][s4], Lacc, 0, 0, 0);
    float e[4];
    #pragma unroll
    for (int q = 0; q < 4; ++q) {
      e[q] = exp2f(fminf(fmaf(Lacc[q], sc2, b2s2[j]), 7.93482257f));
      if (MASKED) {
        int kg = kcAbs*64 + kf*16 + (lane >> 4)*4 + q;
        if (kg <= KK) s_acc[j] += e[q];
      } else {
        s_acc[j] += e[q];
      }
    }
    u32 w = __builtin_amdgcn_cvt_pk_fp8_f32(e[0], e[1], 0, false);
    w = __builtin_amdgcn_cvt_pk_fp8_f32(e[2], e[3], w, true);
    int kl = kf*16 + (lane >> 4)*4;
    *(u32*)(psbuf + pr*72 + kl) = w;   // 72B pitch: conflict-free
  }
}

__global__ __launch_bounds__(512, 4) void fused_kernel(
    const u8* __restrict__ hbuf8,   // [b][34][kf4][s44][64][8] fp8(4h)
    const u8* __restrict__ w2T8,    // [896][128] fp8(16w2)
    const u8* __restrict__ allTT,   // [b][34][cgrp32][sl2][64][8] fp8
    const float* __restrict__ b2, const float* __restrict__ scalep,
    float* __restrict__ out)
{
  __shared__ u8 ps[2][64*72];    // 9 KB
  __shared__ float sums[64];

  int lg = (blockIdx.x & 7)*104 + (blockIdx.x >> 3);   // bijective: 832 = 8*104
  int b = lg / 13;
  int pt = lg - b*13;
  int p0 = pt*64;

  int tid = threadIdx.x, lane = tid & 63, wave = tid >> 6;
  int kf = wave & 3;
  int pfb = (wave >> 2)*2;
  int cw = wave*64;

  const u8* abt = allTT + (size_t)b*NCH*(CC*64);

  if (tid < 64) sums[tid] = 0.f;

  // K-invariant w2 fragments in registers (loaded once)
  long w2f[2][4];
  #pragma unroll
  for (int j = 0; j < 2; ++j) {
    int pr = p0 + (pfb + j)*16 + (lane & 15);
    #pragma unroll
    for (int s4 = 0; s4 < 4; ++s4)
      w2f[j][s4] = *(const long*)(w2T8 + (size_t)pr*HP + (s4*4 + (lane >> 4))*8);
  }

  // af fragment loads: contiguous 512B per (kf,s4)
  const u8* ab = hbuf8 + (size_t)b*NCH*8192 + (size_t)kf*2048 + lane*8;
  long af[4];
  #pragma unroll
  for (int s4 = 0; s4 < 4; ++s4) af[s4] = *(const long*)(ab + s4*512);

  float sclog = scalep[0] * 1.44269504f;
  float sc2 = sclog * (1.0f/64.0f);        // operand scales 4 (h) * 16 (w2)
  float b2s2[2];
  #pragma unroll
  for (int j = 0; j < 2; ++j) {
    int gp = p0 + (pfb + j)*16 + (lane & 15);
    b2s2[j] = ((gp < PPQ) ? b2[gp] : 0.f) * sclog;
  }

  float s_acc[2] = {0.f, 0.f};
  f32x4 acc[4][4];
  #pragma unroll
  for (int pf = 0; pf < 4; ++pf)
    #pragma unroll
    for (int cf = 0; cf < 4; ++cf) acc[pf][cf] = (f32x4){0.f,0.f,0.f,0.f};

  for (int kc = 0; kc < NRUN; ++kc) {
    int pcur = kc & 1;

    if (kc < NRUN - 1)
      v9_logits<false>(af, w2f, b2s2, sc2, kc, kf, pfb, lane, s_acc, ps[pcur]);
    else
      v9_logits<true>(af, w2f, b2s2, sc2, kc, kf, pfb, lane, s_acc, ps[pcur]);

    // rotate af -> kc+1 (hidden under barrier + PV)
    if (kc + 1 < NRUN) {
      ab += 8192;
      #pragma unroll
      for (int s4 = 0; s4 < 4; ++s4) af[s4] = *(const long*)(ab + s4*512);
    }

    // prefetch PV B-frags: contiguous 512B per (cgrp, sl)
    const u8* avb = abt + (size_t)kc*(CC*64);
    long bv0[4], bv1[4];
    #pragma unroll
    for (int cf = 0; cf < 4; ++cf) {
      const u8* cb = avb + (size_t)(wave*4 + cf)*1024 + lane*8;
      bv0[cf] = *(const long*)(cb);
      bv1[cf] = *(const long*)(cb + 512);
    }

    asm volatile("s_waitcnt lgkmcnt(0)" ::: "memory");
    __builtin_amdgcn_sched_barrier(0);
    __builtin_amdgcn_s_barrier();          // ps[pcur] ready everywhere
    __builtin_amdgcn_sched_barrier(0);

    // PV(kc): 32 fp8 MFMA
    #pragma unroll
    for (int sl = 0; sl < 2; ++sl) {
      int koff = sl*32 + (lane >> 4)*8;
      long pa[4];
      #pragma unroll
      for (int pf = 0; pf < 4; ++pf)
        pa[pf] = *(const long*)(ps[pcur] + (pf*16 + (lane & 15))*72 + koff);
      __builtin_amdgcn_s_setprio(1);
      #pragma unroll
      for (int cf = 0; cf < 4; ++cf) {
        long bv = sl ? bv1[cf] : bv0[cf];
        #pragma unroll
        for (int pf = 0; pf < 4; ++pf)
          acc[pf][cf] = __builtin_amdgcn_mfma_f32_16x16x32_fp8_fp8(pa[pf], bv, acc[pf][cf], 0, 0, 0);
      }
      __builtin_amdgcn_s_setprio(0);
    }
  }

  // block-local exp sums
  #pragma unroll
  for (int j = 0; j < 2; ++j) {
    float s = s_acc[j];
    s += __shfl_xor(s, 16);
    s += __shfl_xor(s, 32);
    if (lane < 16) atomicAdd(&sums[(pfb + j)*16 + lane], s);
  }
  __syncthreads();

  // normalize + store
  #pragma unroll
  for (int pf = 0; pf < 4; ++pf)
    #pragma unroll
    for (int q = 0; q < 4; ++q) {
      int pl = pf*16 + (lane >> 4)*4 + q;
      int gp = p0 + pl;
      if (gp < PPQ) {
        float inv = 1.0f / sums[pl];
        #pragma unroll
        for (int cf = 0; cf < 4; ++cf) {
          int c = cw + cf*16 + (lane & 15);
          out[(size_t)b*PPQ*CC + (size_t)gp*CC + c] = acc[pf][cf][q]*inv;
        }
      }
    }
}

extern "C" void kernel_launch(void* const* d_in, const int* in_sizes, int n_in,
                              void* d_out, int out_size, void* d_ws, size_t ws_size,
                              hipStream_t stream)
{
  const float* tokens = (const float*)d_in[0];
  const float* ax  = (const float*)d_in[1];
  const float* ay  = (const float*)d_in[2];
  const float* ln_g = (const float*)d_in[3];
  const float* ln_b = (const float*)d_in[4];
  const float* w1  = (const float*)d_in[5];
  const float* b1  = (const float*)d_in[6];
  const float* w2  = (const float*)d_in[7];
  const float* b2  = (const float*)d_in[8];
  const float* scale = (const float*)d_in[9];
  float* out_super = (float*)d_out;
  float* out_mask  = out_super + (size_t)NB*PPQ*CC;

  char* ws = (char*)d_ws;
  size_t off = 0;
  u64* keys = (u64*)(ws + off);           off += (size_t)NB*LL*8;
  float2* stats = (float2*)(ws + off);    off += 512;
  float* partials = (float*)(ws + off);   off += (size_t)NB*8*CC*4;
  u8*  allTT = (u8*)(ws + off);           off += (size_t)NB*NCH*CC*64;
  u8*  hbuf8 = (u8*)(ws + off);           off += (size_t)NB*NCH*8192;
  u16* w1T   = (u16*)(ws + off);          off += (size_t)HP*CC*2;
  u8*  w2T8  = (u8*)(ws + off);           off += (size_t)PPAD*HP;
  if (off > ws_size) return;

  sort_prep_kernel<<<NB + 176, 1024, 0, stream>>>(
      ax, ay, keys, out_mask, stats, w1, w2, w1T, w2T8);
  tail_partial_kernel<<<dim3(8, NB), 256, 0, stream>>>(tokens, keys, stats, partials);
  gather_ln_mlp_kernel<<<dim3(KP/64, NB), 512, 0, stream>>>(
      tokens, keys, partials, w1T, b1, ln_g, ln_b, allTT, hbuf8);
  fused_kernel<<<NB*NPT, 512, 0, stream>>>(
      hbuf8, w2T8, allTT, b2, scale, out_super);
}

// Round 17
// 400.741 us; speedup vs baseline: 1.0471x; 1.0471x over previous
//
#include <hip/hip_runtime.h>

typedef unsigned char u8;
typedef unsigned short u16;
typedef unsigned int u32;
typedef unsigned long long u64;
typedef __attribute__((ext_vector_type(8))) short short8;
typedef __attribute__((ext_vector_type(4))) float f32x4;

#define NB 64
#define LL 4096
#define CC 512
#define KK 2048     // kept tokens (extra token at row KK)
#define PPQ 819     // P
#define HH 102      // H
#define KP 2176     // padded all_tokens rows (34*64)
#define PPAD 896    // padded P
#define HP 128      // padded H
#define NCH 34      // 64-k chunks in KP (layout)
#define NRUN 33     // chunks processed (covers k <= 2111; rest all-zero)
#define NPT 13      // p-tiles of 64

__device__ __forceinline__ u16 f2bf(float f) {
  u32 u = __float_as_uint(f);
  u += 0x7fffu + ((u >> 16) & 1u);
  return (u16)(u >> 16);
}
__device__ __forceinline__ float bf2f(u16 h) { return __uint_as_float(((u32)h) << 16); }
__device__ __forceinline__ float dec_score(u32 s) {
  u32 u = (s & 0x80000000u) ? (s ^ 0x80000000u) : ~s;
  return __uint_as_float(u);
}
__device__ __forceinline__ u8 f2fp8(float f) {
  return (u8)(__builtin_amdgcn_cvt_pk_fp8_f32(f, 0.f, 0, false) & 0xff);
}

// ---------- sort (blocks 0..63) + weight prep (blocks 64..239) ----------
__global__ __launch_bounds__(1024) void sort_prep_kernel(
    const float* __restrict__ ax, const float* __restrict__ ay,
    u64* __restrict__ keys, float* __restrict__ mask_out, float2* __restrict__ stats,
    const float* __restrict__ w1, const float* __restrict__ w2,
    u16* __restrict__ w1T, u8* __restrict__ w2T8)
{
  if (blockIdx.x >= NB) {
    int id = (blockIdx.x - NB)*1024 + threadIdx.x;
    if (id < HP*CC) {
      int r = id >> 9, c = id & 511;
      w1T[id] = (r < HH) ? f2bf(w1[c*HH + r]) : (u16)0;
    } else {
      int id2 = id - HP*CC;
      if (id2 < PPAD*HP) {
        int r = id2 >> 7, c = id2 & 127;
        w2T8[id2] = (r < PPQ && c < HH) ? f2fp8(16.0f*w2[(size_t)c*PPQ + r]) : (u8)0;
      }
    }
    return;
  }
  __shared__ u64 arr[LL];
  __shared__ float red[16];
  int b = blockIdx.x, tid = threadIdx.x;
  for (int i = tid; i < LL; i += 1024) {
    float s = ax[(size_t)b*LL + i] + ay[(size_t)b*LL + i];
    u32 u = __float_as_uint(s);
    u = (u & 0x80000000u) ? ~u : (u | 0x80000000u);
    arr[i] = (((u64)u) << 32) | (u32)(LL - 1 - i);
  }
  __syncthreads();
  for (int k = 2; k <= LL; k <<= 1) {
    for (int j = k >> 1; j > 0; j >>= 1) {
      #pragma unroll
      for (int rep = 0; rep < 4; ++rep) {
        int i = tid + rep * 1024;
        int ixj = i ^ j;
        if (ixj > i) {
          u64 a = arr[i], c = arr[ixj];
          bool desc = ((i & k) == 0);
          if (desc ? (a < c) : (a > c)) { arr[i] = c; arr[ixj] = a; }
        }
      }
      __syncthreads();
    }
  }
  for (int i = tid; i < LL; i += 1024) {
    u64 v = arr[i];
    keys[(size_t)b*LL + i] = v;
    int idx = (LL - 1) - (int)(v & 0xffffffffu);
    mask_out[(size_t)b*LL + idx] = (i < KK) ? 1.0f : 0.0f;
  }
  float m = dec_score((u32)(arr[KK] >> 32));
  float part = 0.f;
  for (int i = KK + tid; i < LL; i += 1024)
    part += expf(dec_score((u32)(arr[i] >> 32)) - m);
  #pragma unroll
  for (int off = 32; off; off >>= 1) part += __shfl_xor(part, off);
  if ((tid & 63) == 0) red[tid >> 6] = part;
  __syncthreads();
  if (tid == 0) {
    float s = 0.f;
    #pragma unroll
    for (int i = 0; i < 16; ++i) s += red[i];
    stats[b] = make_float2(m, s);
  }
}

// ---------- tail weighted partial sums (extra token) ----------
__global__ __launch_bounds__(256) void tail_partial_kernel(
    const float* __restrict__ tokens, const u64* __restrict__ keys,
    const float2* __restrict__ stats, float* __restrict__ partials)
{
  int b = blockIdx.y, rb = blockIdx.x, t = threadIdx.x;
  float m = stats[b].x, inv = 1.0f / stats[b].y;
  const u64* kb = keys + (size_t)b*LL + KK + rb*256;
  float a0 = 0.f, a1 = 0.f;
  #pragma unroll 4
  for (int r = 0; r < 256; ++r) {
    u64 kk = kb[r];
    int idx = (LL - 1) - (int)(kk & 0xffffffffu);
    float w = expf(dec_score((u32)(kk >> 32)) - m) * inv;
    const float* src = tokens + ((size_t)b*LL + idx)*CC;
    a0 += w * src[t];
    a1 += w * src[t + 256];
  }
  float* dst = partials + (size_t)(b*8 + rb)*CC;
  dst[t] = a0; dst[t + 256] = a1;
}

// ---------- gather + LN + transpose-to-fp8 + MLP GEMM ----------
__global__ __launch_bounds__(512) void gather_ln_mlp_kernel(
    const float* __restrict__ tokens, const u64* __restrict__ keys,
    const float* __restrict__ partials,
    const u16* __restrict__ w1T,    // [128][512] bf16
    const float* __restrict__ b1,
    const float* __restrict__ ln_g, const float* __restrict__ ln_b,
    u8* __restrict__ allTT, u8* __restrict__ hbuf8)
{
  __shared__ u16 t[64*512];
  __shared__ float2 rst[64];
  int b = blockIdx.y;
  int r0 = blockIdx.x*64;
  int tid = threadIdx.x, lane = tid & 63, wave = tid >> 6;

  // ---- phase 1 ----
  #pragma unroll
  for (int i = 0; i < 8; ++i) {
    int rr = wave*8 + i;
    int r = r0 + rr;
    float x[8];
    if (r < KK) {
      u64 kk = keys[(size_t)b*LL + r];
      int idx = (LL - 1) - (int)(kk & 0xffffffffu);
      const float* src = tokens + ((size_t)b*LL + idx)*CC + lane*8;
      f32x4 v0 = *(const f32x4*)src;
      f32x4 v1 = *(const f32x4*)(src + 4);
      #pragma unroll
      for (int j = 0; j < 4; ++j) { x[j] = v0[j]; x[j+4] = v1[j]; }
    } else if (r == KK) {
      #pragma unroll
      for (int j = 0; j < 8; ++j) {
        float s = 0.f;
        #pragma unroll
        for (int p = 0; p < 8; ++p) s += partials[(size_t)(b*8 + p)*CC + lane*8 + j];
        x[j] = s;
      }
    } else {
      #pragma unroll
      for (int j = 0; j < 8; ++j) x[j] = 0.f;
    }
    float s = 0.f;
    #pragma unroll
    for (int j = 0; j < 8; ++j) s += x[j];
    #pragma unroll
    for (int off = 32; off; off >>= 1) s += __shfl_xor(s, off);
    float mu = s * (1.0f/CC);
    float vs = 0.f;
    #pragma unroll
    for (int j = 0; j < 8; ++j) { float d = x[j] - mu; vs += d*d; }
    #pragma unroll
    for (int off = 32; off; off >>= 1) vs += __shfl_xor(vs, off);
    float rstd = rsqrtf(vs * (1.0f/CC) + 1e-5f);
    short8 raw;
    #pragma unroll
    for (int j = 0; j < 8; ++j) raw[j] = (short)f2bf(x[j]);
    *(short8*)(t + rr*512 + ((lane ^ (rr & 7)) << 3)) = raw;
    if (lane == 0) rst[rr] = make_float2(mu, rstd);
  }
  __syncthreads();

  // ---- phase 2: column c = tid; allTT fragment layout [cgrp][sl2][lane][8] ----
  {
    int c = tid;
    u8* dstg = allTT + ((size_t)(b*NCH + blockIdx.x))*(CC*64) + (size_t)(c >> 4)*1024;
    int ln16 = c & 15;
    int cu = c >> 3, cl = c & 7;
    float g = ln_g[c], bb = ln_b[c];
    #pragma unroll
    for (int g8 = 0; g8 < 8; ++g8) {
      float f[8];
      int ri[8];
      #pragma unroll
      for (int j = 0; j < 8; ++j) {
        int rr = g8*8 + j;
        ri[j] = rr*512 + (((cu ^ (rr & 7)) << 3) | cl);
        f[j] = bf2f(t[ri[j]]);
      }
      u32 lo = __builtin_amdgcn_cvt_pk_fp8_f32(f[0], f[1], 0, false);
      lo = __builtin_amdgcn_cvt_pk_fp8_f32(f[2], f[3], lo, true);
      u32 hi = __builtin_amdgcn_cvt_pk_fp8_f32(f[4], f[5], 0, false);
      hi = __builtin_amdgcn_cvt_pk_fp8_f32(f[6], f[7], hi, true);
      *(uint2*)(dstg + (g8 >> 2)*512 + (ln16 + (g8 & 3)*16)*8) = make_uint2(lo, hi);
      #pragma unroll
      for (int j = 0; j < 8; ++j) {
        int rr = g8*8 + j;
        float2 st = rst[rr];
        t[ri[j]] = f2bf((f[j] - st.x)*st.y*g + bb);
      }
    }
  }
  __syncthreads();

  // ---- phase 3: 64x128x512 GEMM -> fp8(4*gelu), LDS-restaged coalesced store ----
  {
    int colh = wave*16 + (lane & 15);
    f32x4 hacc[4];
    #pragma unroll
    for (int m = 0; m < 4; ++m) hacc[m] = (f32x4){0.f,0.f,0.f,0.f};
    for (int kt = 0; kt < 16; ++kt) {
      short8 bf = *(const short8*)(w1T + (size_t)colh*CC + kt*32 + (lane >> 4)*8);
      int ku = kt*4 + (lane >> 4);
      #pragma unroll
      for (int m = 0; m < 4; ++m) {
        int row = m*16 + (lane & 15);
        short8 afr = *(const short8*)(t + row*512 + ((ku ^ (row & 7)) << 3));
        hacc[m] = __builtin_amdgcn_mfma_f32_16x16x32_bf16(afr, bf, hacc[m], 0, 0, 0);
      }
    }
    __syncthreads();   // all waves done reading t -> reuse as staging
    u8* stage = (u8*)t;
    float bb = (colh < HH) ? b1[colh] : 0.f;
    int s4 = colh >> 5;
    int lq = (colh >> 3) & 3;
    int hbyte = colh & 7;
    #pragma unroll
    for (int m = 0; m < 4; ++m)
      #pragma unroll
      for (int q = 0; q < 4; ++q) {
        int rk = m*16 + (lane >> 4)*4 + q;
        float rv = 0.f;
        if (colh < HH) {
          float xx = hacc[m][q] + bb;
          rv = 0.5f*xx*(1.0f + erff(xx*0.70710678118654752f));
        }
        stage[((rk >> 4)*4 + s4)*512 + ((rk & 15) + lq*16)*8 + hbyte] = f2fp8(4.0f*rv);
      }
    __syncthreads();
    u8* hb = hbuf8 + (size_t)(b*NCH + blockIdx.x)*8192;
    *(uint4*)(hb + tid*16) = *(const uint4*)(stage + tid*16);
  }
}

// ---------- fused v10 (r13 verbatim): fragment-layout operands, 1 barrier/chunk ----------
template<bool MASKED>
__device__ __forceinline__ void v9_logits(
    const long (&af)[4], const u8* w2s, const float (&b2s2)[2],
    float sc2, int kcAbs, int kf, int pfb, int lane,
    float (&s_acc)[2], u8* psbuf)
{
  #pragma unroll
  for (int j = 0; j < 2; ++j) {
    int pr = (pfb + j)*16 + (lane & 15);
    long wf[4];
    #pragma unroll
    for (int s4 = 0; s4 < 4; ++s4)
      wf[s4] = *(const long*)(w2s + pr*128 + (((s4*4 + (lane >> 4)) ^ (pr & 14))*8));
    f32x4 Lacc = (f32x4){0.f,0.f,0.f,0.f};
    __builtin_amdgcn_s_setprio(1);
    #pragma unroll
    for (int s4 = 0; s4 < 4; ++s4)
      Lacc = __builtin_amdgcn_mfma_f32_16x16x32_fp8_fp8(af[s4], wf[s4], Lacc, 0, 0, 0);
    __builtin_amdgcn_s_setprio(0);
    float e[4];
    #pragma unroll
    for (int q = 0; q < 4; ++q) {
      e[q] = exp2f(fminf(fmaf(Lacc[q], sc2, b2s2[j]), 7.93482257f));
      if (MASKED) {
        int kg = kcAbs*64 + kf*16 + (lane >> 4)*4 + q;
        if (kg <= KK) s_acc[j] += e[q];
      } else {
        s_acc[j] += e[q];
      }
    }
    u32 w = __builtin_amdgcn_cvt_pk_fp8_f32(e[0], e[1], 0, false);
    w = __builtin_amdgcn_cvt_pk_fp8_f32(e[2], e[3], w, true);
    int kl = kf*16 + (lane >> 4)*4;
    *(u32*)(psbuf + pr*72 + kl) = w;   // 72B pitch: conflict-free
  }
}

__global__ __launch_bounds__(512, 4) void fused_kernel(
    const u8* __restrict__ hbuf8,   // [b][34][kf4][s44][64][8] fp8(4h)
    const u8* __restrict__ w2T8,    // [896][128] fp8(16w2)
    const u8* __restrict__ allTT,   // [b][34][cgrp32][sl2][64][8] fp8
    const float* __restrict__ b2, const float* __restrict__ scalep,
    float* __restrict__ out)
{
  __shared__ u8 w2s[64*128];     // 8 KB, 8B units XOR (row&14)
  __shared__ u8 ps[2][64*72];    // 9 KB
  __shared__ float sums[64];

  int lg = (blockIdx.x & 7)*104 + (blockIdx.x >> 3);   // bijective: 832 = 8*104
  int b = lg / 13;
  int pt = lg - b*13;
  int p0 = pt*64;

  int tid = threadIdx.x, lane = tid & 63, wave = tid >> 6;
  int kf = wave & 3;
  int pfb = (wave >> 2)*2;
  int cw = wave*64;

  const u8* abt = allTT + (size_t)b*NCH*(CC*64);

  // stage w2 tile (swizzled 8B units)
  {
    int row = tid >> 3, u2 = (tid & 7)*2;
    uint4 v = *(const uint4*)(w2T8 + (size_t)(p0 + row)*HP + u2*8);
    *(uint4*)(w2s + row*128 + ((u2 ^ (row & 14))*8)) = v;
  }
  if (tid < 64) sums[tid] = 0.f;

  // af fragment loads: contiguous 512B per (kf,s4)
  const u8* ab = hbuf8 + (size_t)b*NCH*8192 + (size_t)kf*2048 + lane*8;
  long af[4];
  #pragma unroll
  for (int s4 = 0; s4 < 4; ++s4) af[s4] = *(const long*)(ab + s4*512);

  float sclog = scalep[0] * 1.44269504f;
  float sc2 = sclog * (1.0f/64.0f);        // operand scales 4 (h) * 16 (w2)
  float b2s2[2];
  #pragma unroll
  for (int j = 0; j < 2; ++j) {
    int gp = p0 + (pfb + j)*16 + (lane & 15);
    b2s2[j] = ((gp < PPQ) ? b2[gp] : 0.f) * sclog;
  }

  float s_acc[2] = {0.f, 0.f};
  f32x4 acc[4][4];
  #pragma unroll
  for (int pf = 0; pf < 4; ++pf)
    #pragma unroll
    for (int cf = 0; cf < 4; ++cf) acc[pf][cf] = (f32x4){0.f,0.f,0.f,0.f};

  __syncthreads();   // w2s visible

  for (int kc = 0; kc < NRUN; ++kc) {
    int pcur = kc & 1;

    if (kc < NRUN - 1)
      v9_logits<false>(af, w2s, b2s2, sc2, kc, kf, pfb, lane, s_acc, ps[pcur]);
    else
      v9_logits<true>(af, w2s, b2s2, sc2, kc, kf, pfb, lane, s_acc, ps[pcur]);

    // rotate af -> kc+1 (hidden under barrier + PV)
    if (kc + 1 < NRUN) {
      ab += 8192;
      #pragma unroll
      for (int s4 = 0; s4 < 4; ++s4) af[s4] = *(const long*)(ab + s4*512);
    }

    // prefetch PV B-frags: contiguous 512B per (cgrp, sl)
    const u8* avb = abt + (size_t)kc*(CC*64);
    long bv0[4], bv1[4];
    #pragma unroll
    for (int cf = 0; cf < 4; ++cf) {
      const u8* cb = avb + (size_t)(wave*4 + cf)*1024 + lane*8;
      bv0[cf] = *(const long*)(cb);
      bv1[cf] = *(const long*)(cb + 512);
    }

    asm volatile("s_waitcnt lgkmcnt(0)" ::: "memory");
    __builtin_amdgcn_sched_barrier(0);
    __builtin_amdgcn_s_barrier();          // ps[pcur] ready everywhere
    __builtin_amdgcn_sched_barrier(0);

    // PV(kc): 32 fp8 MFMA
    #pragma unroll
    for (int sl = 0; sl < 2; ++sl) {
      int koff = sl*32 + (lane >> 4)*8;
      long pa[4];
      #pragma unroll
      for (int pf = 0; pf < 4; ++pf)
        pa[pf] = *(const long*)(ps[pcur] + (pf*16 + (lane & 15))*72 + koff);
      __builtin_amdgcn_s_setprio(1);
      #pragma unroll
      for (int cf = 0; cf < 4; ++cf) {
        long bv = sl ? bv1[cf] : bv0[cf];
        #pragma unroll
        for (int pf = 0; pf < 4; ++pf)
          acc[pf][cf] = __builtin_amdgcn_mfma_f32_16x16x32_fp8_fp8(pa[pf], bv, acc[pf][cf], 0, 0, 0);
      }
      __builtin_amdgcn_s_setprio(0);
    }
  }

  // block-local exp sums
  #pragma unroll
  for (int j = 0; j < 2; ++j) {
    float s = s_acc[j];
    s += __shfl_xor(s, 16);
    s += __shfl_xor(s, 32);
    if (lane < 16) atomicAdd(&sums[(pfb + j)*16 + lane], s);
  }
  __syncthreads();

  // normalize + store
  #pragma unroll
  for (int pf = 0; pf < 4; ++pf)
    #pragma unroll
    for (int q = 0; q < 4; ++q) {
      int pl = pf*16 + (lane >> 4)*4 + q;
      int gp = p0 + pl;
      if (gp < PPQ) {
        float inv = 1.0f / sums[pl];
        #pragma unroll
        for (int cf = 0; cf < 4; ++cf) {
          int c = cw + cf*16 + (lane & 15);
          out[(size_t)b*PPQ*CC + (size_t)gp*CC + c] = acc[pf][cf][q]*inv;
        }
      }
    }
}

extern "C" void kernel_launch(void* const* d_in, const int* in_sizes, int n_in,
                              void* d_out, int out_size, void* d_ws, size_t ws_size,
                              hipStream_t stream)
{
  const float* tokens = (const float*)d_in[0];
  const float* ax  = (const float*)d_in[1];
  const float* ay  = (const float*)d_in[2];
  const float* ln_g = (const float*)d_in[3];
  const float* ln_b = (const float*)d_in[4];
  const float* w1  = (const float*)d_in[5];
  const float* b1  = (const float*)d_in[6];
  const float* w2  = (const float*)d_in[7];
  const float* b2  = (const float*)d_in[8];
  const float* scale = (const float*)d_in[9];
  float* out_super = (float*)d_out;
  float* out_mask  = out_super + (size_t)NB*PPQ*CC;

  char* ws = (char*)d_ws;
  size_t off = 0;
  u64* keys = (u64*)(ws + off);           off += (size_t)NB*LL*8;
  float2* stats = (float2*)(ws + off);    off += 512;
  float* partials = (float*)(ws + off);   off += (size_t)NB*8*CC*4;
  u8*  allTT = (u8*)(ws + off);           off += (size_t)NB*NCH*CC*64;
  u8*  hbuf8 = (u8*)(ws + off);           off += (size_t)NB*NCH*8192;
  u16* w1T   = (u16*)(ws + off);          off += (size_t)HP*CC*2;
  u8*  w2T8  = (u8*)(ws + off);           off += (size_t)PPAD*HP;
  if (off > ws_size) return;

  sort_prep_kernel<<<NB + 176, 1024, 0, stream>>>(
      ax, ay, keys, out_mask, stats, w1, w2, w1T, w2T8);
  tail_partial_kernel<<<dim3(8, NB), 256, 0, stream>>>(tokens, keys, stats, partials);
  gather_ln_mlp_kernel<<<dim3(KP/64, NB), 512, 0, stream>>>(
      tokens, keys, partials, w1T, b1, ln_g, ln_b, allTT, hbuf8);
  fused_kernel<<<NB*NPT, 512, 0, stream>>>(
      hbuf8, w2T8, allTT, b2, scale, out_super);
}

// Round 18
// 400.365 us; speedup vs baseline: 1.0481x; 1.0009x over previous
//
#include <hip/hip_runtime.h>

typedef unsigned char u8;
typedef unsigned short u16;
typedef unsigned int u32;
typedef unsigned long long u64;
typedef __attribute__((ext_vector_type(8))) short short8;
typedef __attribute__((ext_vector_type(4))) float f32x4;

#define NB 64
#define LL 4096
#define CC 512
#define KK 2048     // kept tokens (extra token at row KK)
#define PPQ 819     // P
#define HH 102      // H
#define KP 2176     // padded all_tokens rows (34*64)
#define PPAD 896    // padded P
#define HP 128      // padded H
#define NCH 34      // 64-k chunks in KP (layout)
#define NRUN 33     // chunks processed (covers k <= 2111; rest all-zero)
#define NPT 13      // p-tiles of 64

__device__ __forceinline__ u16 f2bf(float f) {
  u32 u = __float_as_uint(f);
  u += 0x7fffu + ((u >> 16) & 1u);
  return (u16)(u >> 16);
}
__device__ __forceinline__ float bf2f(u16 h) { return __uint_as_float(((u32)h) << 16); }
__device__ __forceinline__ float dec_score(u32 s) {
  u32 u = (s & 0x80000000u) ? (s ^ 0x80000000u) : ~s;
  return __uint_as_float(u);
}
__device__ __forceinline__ u8 f2fp8(float f) {
  return (u8)(__builtin_amdgcn_cvt_pk_fp8_f32(f, 0.f, 0, false) & 0xff);
}

// ---------- sort (blocks 0..63) + weight prep (blocks 64..239) ----------
__global__ __launch_bounds__(1024) void sort_prep_kernel(
    const float* __restrict__ ax, const float* __restrict__ ay,
    u64* __restrict__ keys, float* __restrict__ mask_out, float2* __restrict__ stats,
    const float* __restrict__ w1, const float* __restrict__ w2,
    u16* __restrict__ w1T, u8* __restrict__ w2T8)
{
  if (blockIdx.x >= NB) {
    int id = (blockIdx.x - NB)*1024 + threadIdx.x;
    if (id < HP*CC) {
      int r = id >> 9, c = id & 511;
      w1T[id] = (r < HH) ? f2bf(w1[c*HH + r]) : (u16)0;
    } else {
      int id2 = id - HP*CC;
      if (id2 < PPAD*HP) {
        int r = id2 >> 7, c = id2 & 127;
        w2T8[id2] = (r < PPQ && c < HH) ? f2fp8(16.0f*w2[(size_t)c*PPQ + r]) : (u8)0;
      }
    }
    return;
  }
  __shared__ u64 arr[LL];
  __shared__ float red[16];
  int b = blockIdx.x, tid = threadIdx.x;
  for (int i = tid; i < LL; i += 1024) {
    float s = ax[(size_t)b*LL + i] + ay[(size_t)b*LL + i];
    u32 u = __float_as_uint(s);
    u = (u & 0x80000000u) ? ~u : (u | 0x80000000u);
    arr[i] = (((u64)u) << 32) | (u32)(LL - 1 - i);
  }
  __syncthreads();
  for (int k = 2; k <= LL; k <<= 1) {
    for (int j = k >> 1; j > 0; j >>= 1) {
      #pragma unroll
      for (int rep = 0; rep < 4; ++rep) {
        int i = tid + rep * 1024;
        int ixj = i ^ j;
        if (ixj > i) {
          u64 a = arr[i], c = arr[ixj];
          bool desc = ((i & k) == 0);
          if (desc ? (a < c) : (a > c)) { arr[i] = c; arr[ixj] = a; }
        }
      }
      __syncthreads();
    }
  }
  for (int i = tid; i < LL; i += 1024) {
    u64 v = arr[i];
    keys[(size_t)b*LL + i] = v;
    int idx = (LL - 1) - (int)(v & 0xffffffffu);
    mask_out[(size_t)b*LL + idx] = (i < KK) ? 1.0f : 0.0f;
  }
  float m = dec_score((u32)(arr[KK] >> 32));
  float part = 0.f;
  for (int i = KK + tid; i < LL; i += 1024)
    part += expf(dec_score((u32)(arr[i] >> 32)) - m);
  #pragma unroll
  for (int off = 32; off; off >>= 1) part += __shfl_xor(part, off);
  if ((tid & 63) == 0) red[tid >> 6] = part;
  __syncthreads();
  if (tid == 0) {
    float s = 0.f;
    #pragma unroll
    for (int i = 0; i < 16; ++i) s += red[i];
    stats[b] = make_float2(m, s);
  }
}

// ---------- tail weighted partial sums (extra token) ----------
__global__ __launch_bounds__(256) void tail_partial_kernel(
    const float* __restrict__ tokens, const u64* __restrict__ keys,
    const float2* __restrict__ stats, float* __restrict__ partials)
{
  int b = blockIdx.y, rb = blockIdx.x, t = threadIdx.x;
  float m = stats[b].x, inv = 1.0f / stats[b].y;
  const u64* kb = keys + (size_t)b*LL + KK + rb*256;
  float a0 = 0.f, a1 = 0.f;
  #pragma unroll 4
  for (int r = 0; r < 256; ++r) {
    u64 kk = kb[r];
    int idx = (LL - 1) - (int)(kk & 0xffffffffu);
    float w = expf(dec_score((u32)(kk >> 32)) - m) * inv;
    const float* src = tokens + ((size_t)b*LL + idx)*CC;
    a0 += w * src[t];
    a1 += w * src[t + 256];
  }
  float* dst = partials + (size_t)(b*8 + rb)*CC;
  dst[t] = a0; dst[t + 256] = a1;
}

// ---------- gather + LN + transpose-to-fp8 + MLP GEMM ----------
__global__ __launch_bounds__(512) void gather_ln_mlp_kernel(
    const float* __restrict__ tokens, const u64* __restrict__ keys,
    const float* __restrict__ partials,
    const u16* __restrict__ w1T,    // [128][512] bf16
    const float* __restrict__ b1,
    const float* __restrict__ ln_g, const float* __restrict__ ln_b,
    u8* __restrict__ allTT, u8* __restrict__ hbuf8)
{
  __shared__ u16 t[64*512];
  __shared__ float2 rst[64];
  int b = blockIdx.y;
  int r0 = blockIdx.x*64;
  int tid = threadIdx.x, lane = tid & 63, wave = tid >> 6;

  // ---- phase 1 ----
  #pragma unroll
  for (int i = 0; i < 8; ++i) {
    int rr = wave*8 + i;
    int r = r0 + rr;
    float x[8];
    if (r < KK) {
      u64 kk = keys[(size_t)b*LL + r];
      int idx = (LL - 1) - (int)(kk & 0xffffffffu);
      const float* src = tokens + ((size_t)b*LL + idx)*CC + lane*8;
      f32x4 v0 = *(const f32x4*)src;
      f32x4 v1 = *(const f32x4*)(src + 4);
      #pragma unroll
      for (int j = 0; j < 4; ++j) { x[j] = v0[j]; x[j+4] = v1[j]; }
    } else if (r == KK) {
      #pragma unroll
      for (int j = 0; j < 8; ++j) {
        float s = 0.f;
        #pragma unroll
        for (int p = 0; p < 8; ++p) s += partials[(size_t)(b*8 + p)*CC + lane*8 + j];
        x[j] = s;
      }
    } else {
      #pragma unroll
      for (int j = 0; j < 8; ++j) x[j] = 0.f;
    }
    float s = 0.f;
    #pragma unroll
    for (int j = 0; j < 8; ++j) s += x[j];
    #pragma unroll
    for (int off = 32; off; off >>= 1) s += __shfl_xor(s, off);
    float mu = s * (1.0f/CC);
    float vs = 0.f;
    #pragma unroll
    for (int j = 0; j < 8; ++j) { float d = x[j] - mu; vs += d*d; }
    #pragma unroll
    for (int off = 32; off; off >>= 1) vs += __shfl_xor(vs, off);
    float rstd = rsqrtf(vs * (1.0f/CC) + 1e-5f);
    short8 raw;
    #pragma unroll
    for (int j = 0; j < 8; ++j) raw[j] = (short)f2bf(x[j]);
    *(short8*)(t + rr*512 + ((lane ^ (rr & 7)) << 3)) = raw;
    if (lane == 0) rst[rr] = make_float2(mu, rstd);
  }
  __syncthreads();

  // ---- phase 2: column c = tid; allTT fragment layout [cgrp][sl2][lane][8] ----
  {
    int c = tid;
    u8* dstg = allTT + ((size_t)(b*NCH + blockIdx.x))*(CC*64) + (size_t)(c >> 4)*1024;
    int ln16 = c & 15;
    int cu = c >> 3, cl = c & 7;
    float g = ln_g[c], bb = ln_b[c];
    #pragma unroll
    for (int g8 = 0; g8 < 8; ++g8) {
      float f[8];
      int ri[8];
      #pragma unroll
      for (int j = 0; j < 8; ++j) {
        int rr = g8*8 + j;
        ri[j] = rr*512 + (((cu ^ (rr & 7)) << 3) | cl);
        f[j] = bf2f(t[ri[j]]);
      }
      u32 lo = __builtin_amdgcn_cvt_pk_fp8_f32(f[0], f[1], 0, false);
      lo = __builtin_amdgcn_cvt_pk_fp8_f32(f[2], f[3], lo, true);
      u32 hi = __builtin_amdgcn_cvt_pk_fp8_f32(f[4], f[5], 0, false);
      hi = __builtin_amdgcn_cvt_pk_fp8_f32(f[6], f[7], hi, true);
      *(uint2*)(dstg + (g8 >> 2)*512 + (ln16 + (g8 & 3)*16)*8) = make_uint2(lo, hi);
      #pragma unroll
      for (int j = 0; j < 8; ++j) {
        int rr = g8*8 + j;
        float2 st = rst[rr];
        t[ri[j]] = f2bf((f[j] - st.x)*st.y*g + bb);
      }
    }
  }
  __syncthreads();

  // ---- phase 3: 64x128x512 GEMM -> fp8(4*gelu), LDS-restaged coalesced store ----
  {
    int colh = wave*16 + (lane & 15);
    f32x4 hacc[4];
    #pragma unroll
    for (int m = 0; m < 4; ++m) hacc[m] = (f32x4){0.f,0.f,0.f,0.f};
    for (int kt = 0; kt < 16; ++kt) {
      short8 bf = *(const short8*)(w1T + (size_t)colh*CC + kt*32 + (lane >> 4)*8);
      int ku = kt*4 + (lane >> 4);
      #pragma unroll
      for (int m = 0; m < 4; ++m) {
        int row = m*16 + (lane & 15);
        short8 afr = *(const short8*)(t + row*512 + ((ku ^ (row & 7)) << 3));
        hacc[m] = __builtin_amdgcn_mfma_f32_16x16x32_bf16(afr, bf, hacc[m], 0, 0, 0);
      }
    }
    __syncthreads();   // all waves done reading t -> reuse as staging
    u8* stage = (u8*)t;
    float bb = (colh < HH) ? b1[colh] : 0.f;
    int s4 = colh >> 5;
    int lq = (colh >> 3) & 3;
    int hbyte = colh & 7;
    #pragma unroll
    for (int m = 0; m < 4; ++m)
      #pragma unroll
      for (int q = 0; q < 4; ++q) {
        int rk = m*16 + (lane >> 4)*4 + q;
        float rv = 0.f;
        if (colh < HH) {
          float xx = hacc[m][q] + bb;
          rv = 0.5f*xx*(1.0f + erff(xx*0.70710678118654752f));
        }
        stage[((rk >> 4)*4 + s4)*512 + ((rk & 15) + lq*16)*8 + hbyte] = f2fp8(4.0f*rv);
      }
    __syncthreads();
    u8* hb = hbuf8 + (size_t)(b*NCH + blockIdx.x)*8192;
    *(uint4*)(hb + tid*16) = *(const uint4*)(stage + tid*16);
  }
}

// ---------- fused v10 (r13 verbatim): fragment-layout operands, 1 barrier/chunk ----------
template<bool MASKED>
__device__ __forceinline__ void v9_logits(
    const long (&af)[4], const u8* w2s, const float (&b2s2)[2],
    float sc2, int kcAbs, int kf, int pfb, int lane,
    float (&s_acc)[2], u8* psbuf)
{
  #pragma unroll
  for (int j = 0; j < 2; ++j) {
    int pr = (pfb + j)*16 + (lane & 15);
    long wf[4];
    #pragma unroll
    for (int s4 = 0; s4 < 4; ++s4)
      wf[s4] = *(const long*)(w2s + pr*128 + (((s4*4 + (lane >> 4)) ^ (pr & 14))*8));
    f32x4 Lacc = (f32x4){0.f,0.f,0.f,0.f};
    __builtin_amdgcn_s_setprio(1);
    #pragma unroll
    for (int s4 = 0; s4 < 4; ++s4)
      Lacc = __builtin_amdgcn_mfma_f32_16x16x32_fp8_fp8(af[s4], wf[s4], Lacc, 0, 0, 0);
    __builtin_amdgcn_s_setprio(0);
    float e[4];
    #pragma unroll
    for (int q = 0; q < 4; ++q) {
      e[q] = exp2f(fminf(fmaf(Lacc[q], sc2, b2s2[j]), 7.93482257f));
      if (MASKED) {
        int kg = kcAbs*64 + kf*16 + (lane >> 4)*4 + q;
        if (kg <= KK) s_acc[j] += e[q];
      } else {
        s_acc[j] += e[q];
      }
    }
    u32 w = __builtin_amdgcn_cvt_pk_fp8_f32(e[0], e[1], 0, false);
    w = __builtin_amdgcn_cvt_pk_fp8_f32(e[2], e[3], w, true);
    int kl = kf*16 + (lane >> 4)*4;
    *(u32*)(psbuf + pr*72 + kl) = w;   // 72B pitch: conflict-free
  }
}

__global__ __launch_bounds__(512, 4) void fused_kernel(
    const u8* __restrict__ hbuf8,   // [b][34][kf4][s44][64][8] fp8(4h)
    const u8* __restrict__ w2T8,    // [896][128] fp8(16w2)
    const u8* __restrict__ allTT,   // [b][34][cgrp32][sl2][64][8] fp8
    const float* __restrict__ b2, const float* __restrict__ scalep,
    float* __restrict__ out)
{
  __shared__ u8 w2s[64*128];     // 8 KB, 8B units XOR (row&14)
  __shared__ u8 ps[2][64*72];    // 9 KB
  __shared__ float sums[64];

  int lg = (blockIdx.x & 7)*104 + (blockIdx.x >> 3);   // bijective: 832 = 8*104
  int b = lg / 13;
  int pt = lg - b*13;
  int p0 = pt*64;

  int tid = threadIdx.x, lane = tid & 63, wave = tid >> 6;
  int kf = wave & 3;
  int pfb = (wave >> 2)*2;
  int cw = wave*64;

  const u8* abt = allTT + (size_t)b*NCH*(CC*64);

  // stage w2 tile (swizzled 8B units)
  {
    int row = tid >> 3, u2 = (tid & 7)*2;
    uint4 v = *(const uint4*)(w2T8 + (size_t)(p0 + row)*HP + u2*8);
    *(uint4*)(w2s + row*128 + ((u2 ^ (row & 14))*8)) = v;
  }
  if (tid < 64) sums[tid] = 0.f;

  // af fragment loads: contiguous 512B per (kf,s4)
  const u8* ab = hbuf8 + (size_t)b*NCH*8192 + (size_t)kf*2048 + lane*8;
  long af[4];
  #pragma unroll
  for (int s4 = 0; s4 < 4; ++s4) af[s4] = *(const long*)(ab + s4*512);

  float sclog = scalep[0] * 1.44269504f;
  float sc2 = sclog * (1.0f/64.0f);        // operand scales 4 (h) * 16 (w2)
  float b2s2[2];
  #pragma unroll
  for (int j = 0; j < 2; ++j) {
    int gp = p0 + (pfb + j)*16 + (lane & 15);
    b2s2[j] = ((gp < PPQ) ? b2[gp] : 0.f) * sclog;
  }

  float s_acc[2] = {0.f, 0.f};
  f32x4 acc[4][4];
  #pragma unroll
  for (int pf = 0; pf < 4; ++pf)
    #pragma unroll
    for (int cf = 0; cf < 4; ++cf) acc[pf][cf] = (f32x4){0.f,0.f,0.f,0.f};

  __syncthreads();   // w2s visible

  for (int kc = 0; kc < NRUN; ++kc) {
    int pcur = kc & 1;

    if (kc < NRUN - 1)
      v9_logits<false>(af, w2s, b2s2, sc2, kc, kf, pfb, lane, s_acc, ps[pcur]);
    else
      v9_logits<true>(af, w2s, b2s2, sc2, kc, kf, pfb, lane, s_acc, ps[pcur]);

    // rotate af -> kc+1 (hidden under barrier + PV)
    if (kc + 1 < NRUN) {
      ab += 8192;
      #pragma unroll
      for (int s4 = 0; s4 < 4; ++s4) af[s4] = *(const long*)(ab + s4*512);
    }

    // prefetch PV B-frags: contiguous 512B per (cgrp, sl)
    const u8* avb = abt + (size_t)kc*(CC*64);
    long bv0[4], bv1[4];
    #pragma unroll
    for (int cf = 0; cf < 4; ++cf) {
      const u8* cb = avb + (size_t)(wave*4 + cf)*1024 + lane*8;
      bv0[cf] = *(const long*)(cb);
      bv1[cf] = *(const long*)(cb + 512);
    }

    asm volatile("s_waitcnt lgkmcnt(0)" ::: "memory");
    __builtin_amdgcn_sched_barrier(0);
    __builtin_amdgcn_s_barrier();          // ps[pcur] ready everywhere
    __builtin_amdgcn_sched_barrier(0);

    // PV(kc): 32 fp8 MFMA
    #pragma unroll
    for (int sl = 0; sl < 2; ++sl) {
      int koff = sl*32 + (lane >> 4)*8;
      long pa[4];
      #pragma unroll
      for (int pf = 0; pf < 4; ++pf)
        pa[pf] = *(const long*)(ps[pcur] + (pf*16 + (lane & 15))*72 + koff);
      __builtin_amdgcn_s_setprio(1);
      #pragma unroll
      for (int cf = 0; cf < 4; ++cf) {
        long bv = sl ? bv1[cf] : bv0[cf];
        #pragma unroll
        for (int pf = 0; pf < 4; ++pf)
          acc[pf][cf] = __builtin_amdgcn_mfma_f32_16x16x32_fp8_fp8(pa[pf], bv, acc[pf][cf], 0, 0, 0);
      }
      __builtin_amdgcn_s_setprio(0);
    }
  }

  // block-local exp sums
  #pragma unroll
  for (int j = 0; j < 2; ++j) {
    float s = s_acc[j];
    s += __shfl_xor(s, 16);
    s += __shfl_xor(s, 32);
    if (lane < 16) atomicAdd(&sums[(pfb + j)*16 + lane], s);
  }
  __syncthreads();

  // normalize + store
  #pragma unroll
  for (int pf = 0; pf < 4; ++pf)
    #pragma unroll
    for (int q = 0; q < 4; ++q) {
      int pl = pf*16 + (lane >> 4)*4 + q;
      int gp = p0 + pl;
      if (gp < PPQ) {
        float inv = 1.0f / sums[pl];
        #pragma unroll
        for (int cf = 0; cf < 4; ++cf) {
          int c = cw + cf*16 + (lane & 15);
          out[(size_t)b*PPQ*CC + (size_t)gp*CC + c] = acc[pf][cf][q]*inv;
        }
      }
    }
}

extern "C" void kernel_launch(void* const* d_in, const int* in_sizes, int n_in,
                              void* d_out, int out_size, void* d_ws, size_t ws_size,
                              hipStream_t stream)
{
  const float* tokens = (const float*)d_in[0];
  const float* ax  = (const float*)d_in[1];
  const float* ay  = (const float*)d_in[2];
  const float* ln_g = (const float*)d_in[3];
  const float* ln_b = (const float*)d_in[4];
  const float* w1  = (const float*)d_in[5];
  const float* b1  = (const float*)d_in[6];
  const float* w2  = (const float*)d_in[7];
  const float* b2  = (const float*)d_in[8];
  const float* scale = (const float*)d_in[9];
  float* out_super = (float*)d_out;
  float* out_mask  = out_super + (size_t)NB*PPQ*CC;

  char* ws = (char*)d_ws;
  size_t off = 0;
  u64* keys = (u64*)(ws + off);           off += (size_t)NB*LL*8;
  float2* stats = (float2*)(ws + off);    off += 512;
  float* partials = (float*)(ws + off);   off += (size_t)NB*8*CC*4;
  u8*  allTT = (u8*)(ws + off);           off += (size_t)NB*NCH*CC*64;
  u8*  hbuf8 = (u8*)(ws + off);           off += (size_t)NB*NCH*8192;
  u16* w1T   = (u16*)(ws + off);          off += (size_t)HP*CC*2;
  u8*  w2T8  = (u8*)(ws + off);           off += (size_t)PPAD*HP;
  if (off > ws_size) return;

  sort_prep_kernel<<<NB + 176, 1024, 0, stream>>>(
      ax, ay, keys, out_mask, stats, w1, w2, w1T, w2T8);
  tail_partial_kernel<<<dim3(8, NB), 256, 0, stream>>>(tokens, keys, stats, partials);
  gather_ln_mlp_kernel<<<dim3(KP/64, NB), 512, 0, stream>>>(
      tokens, keys, partials, w1T, b1, ln_g, ln_b, allTT, hbuf8);
  fused_kernel<<<NB*NPT, 512, 0, stream>>>(
      hbuf8, w2T8, allTT, b2, scale, out_super);
}